// Round 4
// baseline (12.032 us; speedup 1.0000x reference)
//
#include <hip/hip_runtime.h>

#define NHB 0x7f7f7f7fu
#define HIB 0x80808080u

#if __has_builtin(__builtin_amdgcn_sad_u8)
__device__ __forceinline__ unsigned sad8(unsigned a, unsigned b, unsigned c) {
    return __builtin_amdgcn_sad_u8(a, b, c);
}
#else
__device__ __forceinline__ unsigned sad8(unsigned a, unsigned b, unsigned c) {
    unsigned d;
    asm("v_sad_u8 %0, %1, %2, %3" : "=v"(d) : "v"(a), "v"(b), "v"(c));
    return d;
}
#endif

__device__ __forceinline__ unsigned quantq(float v) {
    // (x * 256).clamp(0, 255) -> truncating int cast (nonneg after clamp)
    v = v * 256.0f;
    v = fminf(fmaxf(v, 0.0f), 255.0f);
    return (unsigned)v;
}

__device__ __forceinline__ unsigned pack4(float a, float b, float c, float d) {
    return quantq(a) | (quantq(b) << 8) | (quantq(c) << 16) | (quantq(d) << 24);
}

// 512 blocks x 512 threads: block = (n, i, j-half). 2 blocks/CU -> phase overlap.
__global__ __launch_bounds__(512) void adder2d_kernel(
    const float* __restrict__ x, const float* __restrict__ W,
    float* __restrict__ out)
{
    const int tid = threadIdx.x;
    const int bid = blockIdx.x;
    const int n  = bid >> 6;          // batch
    const int r  = bid & 63;
    const int i  = r >> 1;            // output row
    const int jh = (r & 1) << 4;      // j base: 0 or 16

    __shared__ unsigned sQW[2304];      // 32 f-rows x 72 u32 (288B rows, byte-packed qW)
    __shared__ unsigned sQX[16 * 96];   // 16 local im2col rows, 384B stride, uint4-granule swizzled
    __shared__ unsigned sRowW[768];     // quantized input rows [c][kh][w] bytes

    // Phase 1a: quantize W -> bytes (u32 m covers W flat [4m..4m+3]; f-row = m/72)
    {
        const float4* W4 = (const float4*)W;
        for (int m = tid; m < 2304; m += 512) {
            float4 w = W4[m];
            sQW[m] = pack4(w.x, w.y, w.z, w.w);
        }
    }
    // Phase 1b: quantize input rows i-1..i+1 (out-of-range rows -> q=0)
    for (int m = tid; m < 768; m += 512) {
        int c = m / 24;
        int rr = m - c * 24;
        int kh = rr >> 3;
        int wq = (rr & 7) << 2;
        int row = i + kh - 1;
        unsigned pv = 0;
        if (row >= 0 && row < 32) {
            float4 v = *(const float4*)&x[((n * 32 + c) * 32 + row) * 32 + wq];
            pv = pack4(v.x, v.y, v.z, v.w);
        }
        sRowW[m] = pv;
    }
    __syncthreads();

    // Phase 2: build 16 local im2col byte rows sQX[jj][k], k = c*9+kh*3+kw,
    // uint4-granule swizzle g^(jj&7)
    {
        const unsigned char* sRow = (const unsigned char*)sRowW;
        for (int m = tid; m < 1152; m += 512) {
            int jj = m / 72;
            int p = m - jj * 72;          // u32 index within logical row (0..71)
            int j = jh + jj;              // global output column
            unsigned v = 0;
#pragma unroll
            for (int e = 0; e < 4; ++e) {
                int k = 4 * p + e;
                int c = k / 9;
                int rem = k - 9 * c;
                int kh = rem / 3;
                int kw = rem - 3 * kh;
                int col = j + kw - 1;
                unsigned bv = (col >= 0 && col < 32) ? (unsigned)sRow[c * 96 + kh * 32 + col] : 0u;
                v |= bv << (8 * e);
            }
            int g = p >> 2, e2 = p & 3;
            sQX[jj * 96 + (((g ^ (jj & 7)) << 2) + e2)] = v;
        }
    }
    __syncthreads();

    // Phase 3: one output per thread. qW reads: 16-lane broadcast, 4 f-rows at
    // distinct bank spans. qX reads: 16 rows, 2-way bank alias (free) + 4-way broadcast.
    const int f = tid >> 4;
    const int jl = tid & 15;
    const int js = jl & 7;
    const uint4* qwr = (const uint4*)&sQW[f * 72];
    const uint4* qxr = (const uint4*)&sQX[jl * 96];
    unsigned acc = 0;   // max 288*255 = 73440 < 2^32
#pragma unroll
    for (int g = 0; g < 18; ++g) {
        uint4 a = qwr[g];
        uint4 b = qxr[g ^ js];
        // exact per-byte (a+b)&255 (no cross-byte carry), then sad sums the 4 bytes
        acc = sad8(((a.x & NHB) + (b.x & NHB)) ^ ((a.x ^ b.x) & HIB), 0u, acc);
        acc = sad8(((a.y & NHB) + (b.y & NHB)) ^ ((a.y ^ b.y) & HIB), 0u, acc);
        acc = sad8(((a.z & NHB) + (b.z & NHB)) ^ ((a.z ^ b.z) & HIB), 0u, acc);
        acc = sad8(((a.w & NHB) + (b.w & NHB)) ^ ((a.w ^ b.w) & HIB), 0u, acc);
    }

    out[((n * 32 + f) * 32 + i) * 32 + jh + jl] = -(float)acc * (1.0f / 256.0f);
}

extern "C" void kernel_launch(void* const* d_in, const int* in_sizes, int n_in,
                              void* d_out, int out_size, void* d_ws, size_t ws_size,
                              hipStream_t stream) {
    const float* x = (const float*)d_in[0];   // [8,32,32,32]
    const float* W = (const float*)d_in[1];   // [32,32,3,3]
    float* out = (float*)d_out;               // [8,32,32,32]
    adder2d_kernel<<<512, 512, 0, stream>>>(x, W, out);
}